// Round 4
// baseline (2107.692 us; speedup 1.0000x reference)
//
#include <hip/hip_runtime.h>
#include <stdint.h>

#define D 128
#define E_EDGES 600000
#define N_USER_C 100000
#define N_ITEM_C 50000
#define NEG_SLOPE 0.01f
#define LN_EPS 1e-5f

#define LDPAD 136            // Wt row pitch (shorts): 16B-aligned rows, 2-way banks max
#define GRID_BLOCKS 1024     // persistent main kernel, 4 blocks/CU
#define GRID_WAVES (GRID_BLOCKS * 4)

typedef __attribute__((ext_vector_type(8))) short bf16x8;
typedef __attribute__((ext_vector_type(4))) float f32x4;
typedef __attribute__((ext_vector_type(4))) uint32_t u32x4;

__device__ inline short f2bf(float f) {
    uint32_t u = __builtin_bit_cast(uint32_t, f);
    u += 0x7fffu + ((u >> 16) & 1u);
    return (short)(u >> 16);
}
__device__ inline uint32_t pack2f(float a, float b) {
    return (uint32_t)(uint16_t)f2bf(a) | ((uint32_t)(uint16_t)f2bf(b) << 16);
}

// ---------------- counting sort by dst ----------------

__global__ void hist_k(const int* __restrict__ dst, int* __restrict__ counts, int n) {
    int e = blockIdx.x * 256 + threadIdx.x;
    if (e < n) atomicAdd(&counts[dst[e]], 1);
}

// per-1024-block exclusive scan; block totals to partial[]
__global__ void scan_block_k(const int* __restrict__ counts, int* __restrict__ offsets,
                             int* __restrict__ partial, int n) {
    __shared__ int sm[1024];
    const int t = threadIdx.x;
    const int i = blockIdx.x * 1024 + t;
    int v = (i < n) ? counts[i] : 0;
    sm[t] = v;
    __syncthreads();
    for (int off = 1; off < 1024; off <<= 1) {
        int x = (t >= off) ? sm[t - off] : 0;
        __syncthreads();
        sm[t] += x;
        __syncthreads();
    }
    if (i < n) offsets[i] = sm[t] - v;          // exclusive within block
    if (t == 1023) partial[blockIdx.x] = sm[t]; // block total
}

// single-block exclusive scan of block totals (nb <= 128)
__global__ void scan_part_k(int* __restrict__ partial, int nb) {
    __shared__ int sm[128];
    const int t = threadIdx.x;
    int v = (t < nb) ? partial[t] : 0;
    sm[t] = v;
    __syncthreads();
    for (int off = 1; off < 128; off <<= 1) {
        int x = (t >= off) ? sm[t - off] : 0;
        __syncthreads();
        sm[t] += x;
        __syncthreads();
    }
    if (t < nb) partial[t] = sm[t] - v;
}

// add block bases; also zero counts for reuse as scatter cursors
__global__ void scan_add_k(int* __restrict__ offsets, const int* __restrict__ partial,
                           int* __restrict__ counts, int n) {
    const int i = blockIdx.x * 1024 + threadIdx.x;
    if (i < n) {
        offsets[i] += partial[blockIdx.x];
        counts[i] = 0;
    }
}

__global__ void scatter_k(const int* __restrict__ src, const int* __restrict__ dst,
                          const int* __restrict__ offsets, int* __restrict__ counts,
                          int* __restrict__ sorted, int n) {
    int e = blockIdx.x * 256 + threadIdx.x;
    if (e < n) {
        int d = dst[e];
        int pos = offsets[d] + atomicAdd(&counts[d], 1);
        sorted[pos] = src[e];
    }
}

// ---------------- segment-reduced NGCF conv + fused LayerNorm/ReLU ----------------
// One wave per dst node d: dst row in registers; per 16-edge chunk gather src
// rows, products -> bf16 A-fragments, MFMA vs LDS W^T, bias+LeakyReLU on valid
// rows, masked in-register segment sum. Epilogue: LN(mode=node)+ReLU, store.
// Zero atomics; d_out written exactly once (no memset needed).
__global__ __launch_bounds__(256, 4) void ngcf_seg(
    const float* __restrict__ xsrc, const float* __restrict__ xdst,
    const float* __restrict__ W, const float* __restrict__ bias,
    const int* __restrict__ offsets, const int* __restrict__ sorted,
    const float* __restrict__ lnw, const float* __restrict__ lnb,
    float* __restrict__ outp, int n_dst, int n_edges)
{
    __shared__ short Wt[128 * LDPAD];   // Wt[n][k] = W[k][n], bf16

    const int t = threadIdx.x;
    for (int i = t; i < 128 * 128; i += 256) {
        int k = i >> 7, n = i & 127;
        Wt[n * LDPAD + k] = f2bf(W[i]);
    }
    __syncthreads();   // only barrier; Wt read-only afterwards

    const int wv   = t >> 6;
    const int l    = t & 63;
    const int lo16 = l & 15;
    const int quad = l >> 4;

    float bn[8];
    #pragma unroll
    for (int n = 0; n < 8; n++) bn[n] = bias[n * 16 + lo16];

    for (int d = blockIdx.x * 4 + wv; d < n_dst; d += GRID_WAVES) {
        const int start = offsets[d];
        const int end   = (d + 1 < n_dst) ? offsets[d + 1] : n_edges;
        const int len   = end - start;

        // dst row k-slices for this lane (fp32, reused across all chunks)
        const float4* pd = (const float4*)(xdst + ((size_t)d << 7));
        float4 dr[8];
        #pragma unroll
        for (int kt = 0; kt < 4; kt++) {
            dr[kt * 2 + 0] = pd[kt * 8 + quad * 2 + 0];
            dr[kt * 2 + 1] = pd[kt * 8 + quad * 2 + 1];
        }

        float nacc[8];
        #pragma unroll
        for (int n = 0; n < 8; n++) nacc[n] = 0.f;

        for (int c0 = 0; c0 < len; c0 += 16) {
            const int eidx = c0 + lo16;
            const int si = (eidx < len) ? sorted[start + eidx] : 0;
            const float4* ps = (const float4*)(xsrc + ((size_t)si << 7));

            f32x4 acc[8];
            #pragma unroll
            for (int n = 0; n < 8; n++) acc[n] = (f32x4){0.f, 0.f, 0.f, 0.f};

            #pragma unroll
            for (int kt = 0; kt < 4; kt++) {
                float4 a0 = ps[kt * 8 + quad * 2 + 0];
                float4 a1 = ps[kt * 8 + quad * 2 + 1];
                float4 c0v = dr[kt * 2 + 0];
                float4 c1v = dr[kt * 2 + 1];
                u32x4 up;
                up[0] = pack2f(a0.x * c0v.x, a0.y * c0v.y);
                up[1] = pack2f(a0.z * c0v.z, a0.w * c0v.w);
                up[2] = pack2f(a1.x * c1v.x, a1.y * c1v.y);
                up[3] = pack2f(a1.z * c1v.z, a1.w * c1v.w);
                bf16x8 afrag = __builtin_bit_cast(bf16x8, up);
                #pragma unroll
                for (int n = 0; n < 8; n++) {
                    bf16x8 bfrag = *(const bf16x8*)&Wt[(n * 16 + lo16) * LDPAD + kt * 32 + quad * 8];
                    acc[n] = __builtin_amdgcn_mfma_f32_16x16x32_bf16(afrag, bfrag, acc[n], 0, 0, 0);
                }
            }

            // bias + LeakyReLU per valid edge-row, masked segment sum.
            // C/D layout: col = n*16+lo16, row = quad*4+r (row = edge c0+row)
            const int rem = len - c0;
            #pragma unroll
            for (int r = 0; r < 4; r++) {
                const bool ok = (quad * 4 + r) < rem;
                #pragma unroll
                for (int n = 0; n < 8; n++) {
                    float v = acc[n][r] + bn[n];
                    v = v > 0.f ? v : NEG_SLOPE * v;
                    nacc[n] += ok ? v : 0.f;
                }
            }
        }

        // reduce partial sums across the 4 quads (rows live in different quads)
        #pragma unroll
        for (int n = 0; n < 8; n++) {
            nacc[n] += __shfl_xor(nacc[n], 16);
            nacc[n] += __shfl_xor(nacc[n], 32);
        }

        // fused LayerNorm(node) + ReLU. After quad-reduce, lane(lo16,*) holds
        // cols {n*16+lo16}; xor over bits 0..3 sums the 16 lo16 groups -> 128 cols.
        float s1 = 0.f, s2 = 0.f;
        #pragma unroll
        for (int n = 0; n < 8; n++) { s1 += nacc[n]; s2 += nacc[n] * nacc[n]; }
        #pragma unroll
        for (int off = 1; off <= 8; off <<= 1) {
            s1 += __shfl_xor(s1, off);
            s2 += __shfl_xor(s2, off);
        }
        const float mu  = s1 * (1.0f / 128.0f);
        const float var = s2 * (1.0f / 128.0f) - mu * mu;
        const float rs  = rsqrtf(var + LN_EPS);

        // each lane stores 2 cols: n in {2*quad, 2*quad+1}
        const int n0 = 2 * quad, n1 = n0 + 1;
        const int col0 = n0 * 16 + lo16, col1 = n1 * 16 + lo16;
        float o0 = (nacc[n0] - mu) * rs * lnw[col0] + lnb[col0];
        float o1 = (nacc[n1] - mu) * rs * lnw[col1] + lnb[col1];
        float* rp = outp + ((size_t)d << 7);
        rp[col0] = fmaxf(o0, 0.f);
        rp[col1] = fmaxf(o1, 0.f);
    }
}

// ---------------- launch ----------------

static inline void run_relation(const float* xsrc, const float* xdst,
                                const float* W, const float* bias,
                                const int* src, const int* dst,
                                const float* lnw, const float* lnb,
                                float* outp, int n_dst,
                                int* counts, int* offsets, int* partial, int* sorted,
                                hipStream_t stream) {
    const int nb = (n_dst + 1023) / 1024;
    hipMemsetAsync(counts, 0, (size_t)n_dst * sizeof(int), stream);
    hist_k<<<dim3((E_EDGES + 255) / 256), dim3(256), 0, stream>>>(dst, counts, E_EDGES);
    scan_block_k<<<dim3(nb), dim3(1024), 0, stream>>>(counts, offsets, partial, n_dst);
    scan_part_k<<<dim3(1), dim3(128), 0, stream>>>(partial, nb);
    scan_add_k<<<dim3(nb), dim3(1024), 0, stream>>>(offsets, partial, counts, n_dst);
    scatter_k<<<dim3((E_EDGES + 255) / 256), dim3(256), 0, stream>>>(src, dst, offsets, counts, sorted, E_EDGES);
    ngcf_seg<<<dim3(GRID_BLOCKS), dim3(256), 0, stream>>>(
        xsrc, xdst, W, bias, offsets, sorted, lnw, lnb, outp, n_dst, E_EDGES);
}

extern "C" void kernel_launch(void* const* d_in, const int* in_sizes, int n_in,
                              void* d_out, int out_size, void* d_ws, size_t ws_size,
                              hipStream_t stream) {
    const float* x_user    = (const float*)d_in[0];
    const float* x_item    = (const float*)d_in[1];
    const float* W_ui      = (const float*)d_in[2];
    const float* b_ui      = (const float*)d_in[3];
    const float* W_iu      = (const float*)d_in[4];
    const float* b_iu      = (const float*)d_in[5];
    const float* ln_w_user = (const float*)d_in[6];
    const float* ln_b_user = (const float*)d_in[7];
    const float* ln_w_item = (const float*)d_in[8];
    const float* ln_b_item = (const float*)d_in[9];
    const int* esrc_ui = (const int*)d_in[10];
    const int* edst_ui = (const int*)d_in[11];
    const int* esrc_iu = (const int*)d_in[12];
    const int* edst_iu = (const int*)d_in[13];

    float* out = (float*)d_out;
    float* out_user = out;                          // N_USER x D
    float* out_item = out + (size_t)N_USER_C * D;   // N_ITEM x D

    // ws layout (ints): counts | offsets | partial | sorted  (~3.2 MB, reused per relation)
    int* counts  = (int*)d_ws;
    int* offsets = counts + 100032;
    int* partial = offsets + 100032;
    int* sorted  = partial + 192;

    // relation user->item: aggregate at items, item LN params
    run_relation(x_user, x_item, W_ui, b_ui, esrc_ui, edst_ui,
                 ln_w_item, ln_b_item, out_item, N_ITEM_C,
                 counts, offsets, partial, sorted, stream);
    // relation item->user: aggregate at users, user LN params
    run_relation(x_item, x_user, W_iu, b_iu, esrc_iu, edst_iu,
                 ln_w_user, ln_b_user, out_user, N_USER_C,
                 counts, offsets, partial, sorted, stream);
}

// Round 5
// 1966.335 us; speedup vs baseline: 1.0719x; 1.0719x over previous
//
#include <hip/hip_runtime.h>
#include <stdint.h>

#define D 128
#define E_EDGES 600000
#define N_USER_C 100000
#define N_ITEM_C 50000
#define NEG_SLOPE 0.01f
#define LN_EPS 1e-5f

#define LDPAD 136            // Wt row pitch (shorts): 16B-aligned rows, 2-way banks max
#define GRID_BLOCKS 1024     // persistent main kernel, 4 blocks/CU
#define GRID_WAVES (GRID_BLOCKS * 4)

typedef __attribute__((ext_vector_type(8))) short bf16x8;
typedef __attribute__((ext_vector_type(4))) float f32x4;
typedef __attribute__((ext_vector_type(4))) uint32_t u32x4;

__device__ inline short f2bf(float f) {
    uint32_t u = __builtin_bit_cast(uint32_t, f);
    u += 0x7fffu + ((u >> 16) & 1u);
    return (short)(u >> 16);
}
__device__ inline uint32_t pack2f(float a, float b) {
    return (uint32_t)(uint16_t)f2bf(a) | ((uint32_t)(uint16_t)f2bf(b) << 16);
}

// ---------------- counting sort by dst ----------------

__global__ void hist_k(const int* __restrict__ dst, int* __restrict__ counts, int n) {
    int e = blockIdx.x * 256 + threadIdx.x;
    if (e < n) atomicAdd(&counts[dst[e]], 1);
}

__global__ void scan_block_k(const int* __restrict__ counts, int* __restrict__ offsets,
                             int* __restrict__ partial, int n) {
    __shared__ int sm[1024];
    const int t = threadIdx.x;
    const int i = blockIdx.x * 1024 + t;
    int v = (i < n) ? counts[i] : 0;
    sm[t] = v;
    __syncthreads();
    for (int off = 1; off < 1024; off <<= 1) {
        int x = (t >= off) ? sm[t - off] : 0;
        __syncthreads();
        sm[t] += x;
        __syncthreads();
    }
    if (i < n) offsets[i] = sm[t] - v;          // exclusive within block
    if (t == 1023) partial[blockIdx.x] = sm[t]; // block total
}

__global__ void scan_part_k(int* __restrict__ partial, int nb) {
    __shared__ int sm[128];
    const int t = threadIdx.x;
    int v = (t < nb) ? partial[t] : 0;
    sm[t] = v;
    __syncthreads();
    for (int off = 1; off < 128; off <<= 1) {
        int x = (t >= off) ? sm[t - off] : 0;
        __syncthreads();
        sm[t] += x;
        __syncthreads();
    }
    if (t < nb) partial[t] = sm[t] - v;
}

__global__ void scan_add_k(int* __restrict__ offsets, const int* __restrict__ partial,
                           int* __restrict__ counts, int n) {
    const int i = blockIdx.x * 1024 + threadIdx.x;
    if (i < n) {
        offsets[i] += partial[blockIdx.x];
        counts[i] = 0;
    }
}

__global__ void scatter_k(const int* __restrict__ src, const int* __restrict__ dst,
                          const int* __restrict__ offsets, int* __restrict__ counts,
                          int* __restrict__ sorted, int n) {
    int e = blockIdx.x * 256 + threadIdx.x;
    if (e < n) {
        int d = dst[e];
        int pos = offsets[d] + atomicAdd(&counts[d], 1);
        sorted[pos] = src[e];
    }
}

// ---------------- segment-reduced NGCF conv + fused LayerNorm/ReLU ----------------
// One wave per dst node d. Per 16-edge chunk: gather src rows AND the dst row
// k-slices (transient regs — R4's hoisted dr[8] spilled to scratch, 2.9 GB
// writes), products -> bf16 A-fragments, MFMA vs LDS W^T, bias+LeakyReLU on
// valid rows, masked in-register segment sum. Epilogue: LN(node)+ReLU, store.
// Zero atomics; d_out written exactly once (no memset needed).
__global__ __launch_bounds__(256, 4) void ngcf_seg(
    const float* __restrict__ xsrc, const float* __restrict__ xdst,
    const float* __restrict__ W, const float* __restrict__ bias,
    const int* __restrict__ offsets, const int* __restrict__ sorted,
    const float* __restrict__ lnw, const float* __restrict__ lnb,
    float* __restrict__ outp, int n_dst, int n_edges)
{
    __shared__ short Wt[128 * LDPAD];   // Wt[n][k] = W[k][n], bf16

    const int t = threadIdx.x;
    for (int i = t; i < 128 * 128; i += 256) {
        int k = i >> 7, n = i & 127;
        Wt[n * LDPAD + k] = f2bf(W[i]);
    }
    __syncthreads();   // only barrier; Wt read-only afterwards

    const int wv   = t >> 6;
    const int l    = t & 63;
    const int lo16 = l & 15;
    const int quad = l >> 4;

    float bn[8];
    #pragma unroll
    for (int n = 0; n < 8; n++) bn[n] = bias[n * 16 + lo16];

    for (int d = blockIdx.x * 4 + wv; d < n_dst; d += GRID_WAVES) {
        const int start = offsets[d];
        const int end   = (d + 1 < n_dst) ? offsets[d + 1] : n_edges;
        const int len   = end - start;

        const float4* pd = (const float4*)(xdst + ((size_t)d << 7));

        float nacc[8];
        #pragma unroll
        for (int n = 0; n < 8; n++) nacc[n] = 0.f;

        for (int c0 = 0; c0 < len; c0 += 16) {
            const int eidx = c0 + lo16;
            const int si = (eidx < len) ? sorted[start + eidx] : 0;
            const float4* ps = (const float4*)(xsrc + ((size_t)si << 7));

            f32x4 acc[8];
            #pragma unroll
            for (int n = 0; n < 8; n++) acc[n] = (f32x4){0.f, 0.f, 0.f, 0.f};

            #pragma unroll
            for (int kt = 0; kt < 4; kt++) {
                // transient loads only — keeps live range inside the iteration
                float4 a0 = ps[kt * 8 + quad * 2 + 0];
                float4 a1 = ps[kt * 8 + quad * 2 + 1];
                float4 c0v = pd[kt * 8 + quad * 2 + 0];
                float4 c1v = pd[kt * 8 + quad * 2 + 1];
                u32x4 up;
                up[0] = pack2f(a0.x * c0v.x, a0.y * c0v.y);
                up[1] = pack2f(a0.z * c0v.z, a0.w * c0v.w);
                up[2] = pack2f(a1.x * c1v.x, a1.y * c1v.y);
                up[3] = pack2f(a1.z * c1v.z, a1.w * c1v.w);
                bf16x8 afrag = __builtin_bit_cast(bf16x8, up);
                #pragma unroll
                for (int n = 0; n < 8; n++) {
                    bf16x8 bfrag = *(const bf16x8*)&Wt[(n * 16 + lo16) * LDPAD + kt * 32 + quad * 8];
                    acc[n] = __builtin_amdgcn_mfma_f32_16x16x32_bf16(afrag, bfrag, acc[n], 0, 0, 0);
                }
            }

            // bias + LeakyReLU per valid edge-row, masked segment sum.
            // C/D layout: col = n*16+lo16, row = quad*4+r (edge c0+row)
            const int rem = len - c0;
            #pragma unroll
            for (int r = 0; r < 4; r++) {
                const bool ok = (quad * 4 + r) < rem;
                #pragma unroll
                for (int n = 0; n < 8; n++) {
                    float v = acc[n][r] + bn[n];
                    v = v > 0.f ? v : NEG_SLOPE * v;
                    nacc[n] += ok ? v : 0.f;
                }
            }
        }

        // reduce partial sums across the 4 quads (rows live in different quads)
        #pragma unroll
        for (int n = 0; n < 8; n++) {
            nacc[n] += __shfl_xor(nacc[n], 16);
            nacc[n] += __shfl_xor(nacc[n], 32);
        }

        // fused LayerNorm(node) + ReLU. Lane (lo16,*) holds cols {n*16+lo16};
        // xor over bits 0..3 sums the 16 lo16 groups -> all 128 cols.
        float s1 = 0.f, s2 = 0.f;
        #pragma unroll
        for (int n = 0; n < 8; n++) { s1 += nacc[n]; s2 += nacc[n] * nacc[n]; }
        #pragma unroll
        for (int off = 1; off <= 8; off <<= 1) {
            s1 += __shfl_xor(s1, off);
            s2 += __shfl_xor(s2, off);
        }
        const float mu  = s1 * (1.0f / 128.0f);
        const float var = s2 * (1.0f / 128.0f) - mu * mu;
        const float rs  = rsqrtf(var + LN_EPS);

        // each lane stores 2 cols: n in {2*quad, 2*quad+1}
        const int n0 = 2 * quad, n1 = n0 + 1;
        const int col0 = n0 * 16 + lo16, col1 = n1 * 16 + lo16;
        float o0 = (nacc[n0] - mu) * rs * lnw[col0] + lnb[col0];
        float o1 = (nacc[n1] - mu) * rs * lnw[col1] + lnb[col1];
        float* rp = outp + ((size_t)d << 7);
        rp[col0] = fmaxf(o0, 0.f);
        rp[col1] = fmaxf(o1, 0.f);
    }
}

// ---------------- launch ----------------

static inline void run_relation(const float* xsrc, const float* xdst,
                                const float* W, const float* bias,
                                const int* src, const int* dst,
                                const float* lnw, const float* lnb,
                                float* outp, int n_dst,
                                int* counts, int* offsets, int* partial, int* sorted,
                                hipStream_t stream) {
    const int nb = (n_dst + 1023) / 1024;
    hipMemsetAsync(counts, 0, (size_t)n_dst * sizeof(int), stream);
    hist_k<<<dim3((E_EDGES + 255) / 256), dim3(256), 0, stream>>>(dst, counts, E_EDGES);
    scan_block_k<<<dim3(nb), dim3(1024), 0, stream>>>(counts, offsets, partial, n_dst);
    scan_part_k<<<dim3(1), dim3(128), 0, stream>>>(partial, nb);
    scan_add_k<<<dim3(nb), dim3(1024), 0, stream>>>(offsets, partial, counts, n_dst);
    scatter_k<<<dim3((E_EDGES + 255) / 256), dim3(256), 0, stream>>>(src, dst, offsets, counts, sorted, E_EDGES);
    ngcf_seg<<<dim3(GRID_BLOCKS), dim3(256), 0, stream>>>(
        xsrc, xdst, W, bias, offsets, sorted, lnw, lnb, outp, n_dst, E_EDGES);
}

extern "C" void kernel_launch(void* const* d_in, const int* in_sizes, int n_in,
                              void* d_out, int out_size, void* d_ws, size_t ws_size,
                              hipStream_t stream) {
    const float* x_user    = (const float*)d_in[0];
    const float* x_item    = (const float*)d_in[1];
    const float* W_ui      = (const float*)d_in[2];
    const float* b_ui      = (const float*)d_in[3];
    const float* W_iu      = (const float*)d_in[4];
    const float* b_iu      = (const float*)d_in[5];
    const float* ln_w_user = (const float*)d_in[6];
    const float* ln_b_user = (const float*)d_in[7];
    const float* ln_w_item = (const float*)d_in[8];
    const float* ln_b_item = (const float*)d_in[9];
    const int* esrc_ui = (const int*)d_in[10];
    const int* edst_ui = (const int*)d_in[11];
    const int* esrc_iu = (const int*)d_in[12];
    const int* edst_iu = (const int*)d_in[13];

    float* out = (float*)d_out;
    float* out_user = out;                          // N_USER x D
    float* out_item = out + (size_t)N_USER_C * D;   // N_ITEM x D

    // ws layout (ints): counts | offsets | partial | sorted  (~3.2 MB, reused)
    int* counts  = (int*)d_ws;
    int* offsets = counts + 100032;
    int* partial = offsets + 100032;
    int* sorted  = partial + 192;

    // relation user->item: aggregate at items, item LN params
    run_relation(x_user, x_item, W_ui, b_ui, esrc_ui, edst_ui,
                 ln_w_item, ln_b_item, out_item, N_ITEM_C,
                 counts, offsets, partial, sorted, stream);
    // relation item->user: aggregate at users, user LN params
    run_relation(x_item, x_user, W_iu, b_iu, esrc_iu, edst_iu,
                 ln_w_user, ln_b_user, out_user, N_USER_C,
                 counts, offsets, partial, sorted, stream);
}

// Round 6
// 604.039 us; speedup vs baseline: 3.4893x; 3.2553x over previous
//
#include <hip/hip_runtime.h>
#include <stdint.h>

#define D 128
#define E_EDGES 600000
#define N_USER_C 100000
#define N_ITEM_C 50000
#define NEG_SLOPE 0.01f
#define LN_EPS 1e-5f

#define LDPAD 136            // Wt row pitch (shorts): 16B-aligned rows, 2-way banks max
#define GRID_BLOCKS 1024     // persistent main kernel
#define GRID_WAVES (GRID_BLOCKS * 4)

typedef __attribute__((ext_vector_type(8))) short bf16x8;
typedef __attribute__((ext_vector_type(4))) float f32x4;
typedef __attribute__((ext_vector_type(4))) uint32_t u32x4;

__device__ inline short f2bf(float f) {
    uint32_t u = __builtin_bit_cast(uint32_t, f);
    u += 0x7fffu + ((u >> 16) & 1u);
    return (short)(u >> 16);
}
__device__ inline uint32_t pack2f(float a, float b) {
    return (uint32_t)(uint16_t)f2bf(a) | ((uint32_t)(uint16_t)f2bf(b) << 16);
}

// ---------------- counting sort by dst ----------------

__global__ void hist_k(const int* __restrict__ dst, int* __restrict__ counts, int n) {
    int e = blockIdx.x * 256 + threadIdx.x;
    if (e < n) atomicAdd(&counts[dst[e]], 1);
}

__global__ void scan_block_k(const int* __restrict__ counts, int* __restrict__ offsets,
                             int* __restrict__ partial, int n) {
    __shared__ int sm[1024];
    const int t = threadIdx.x;
    const int i = blockIdx.x * 1024 + t;
    int v = (i < n) ? counts[i] : 0;
    sm[t] = v;
    __syncthreads();
    for (int off = 1; off < 1024; off <<= 1) {
        int x = (t >= off) ? sm[t - off] : 0;
        __syncthreads();
        sm[t] += x;
        __syncthreads();
    }
    if (i < n) offsets[i] = sm[t] - v;          // exclusive within block
    if (t == 1023) partial[blockIdx.x] = sm[t]; // block total
}

__global__ void scan_part_k(int* __restrict__ partial, int nb) {
    __shared__ int sm[128];
    const int t = threadIdx.x;
    int v = (t < nb) ? partial[t] : 0;
    sm[t] = v;
    __syncthreads();
    for (int off = 1; off < 128; off <<= 1) {
        int x = (t >= off) ? sm[t - off] : 0;
        __syncthreads();
        sm[t] += x;
        __syncthreads();
    }
    if (t < nb) partial[t] = sm[t] - v;
}

__global__ void scan_add_k(int* __restrict__ offsets, const int* __restrict__ partial,
                           int* __restrict__ counts, int n) {
    const int i = blockIdx.x * 1024 + threadIdx.x;
    if (i < n) {
        offsets[i] += partial[blockIdx.x];
        counts[i] = 0;
    }
}

__global__ void scatter_k(const int* __restrict__ src, const int* __restrict__ dst,
                          const int* __restrict__ offsets, int* __restrict__ counts,
                          int* __restrict__ sorted, int n) {
    int e = blockIdx.x * 256 + threadIdx.x;
    if (e < n) {
        int d = dst[e];
        int pos = offsets[d] + atomicAdd(&counts[d], 1);
        sorted[pos] = src[e];
    }
}

// ---------------- segment-reduced NGCF conv + fused LayerNorm/ReLU ----------------
// One wave per dst node d. Per 16-edge chunk: gather src + dst row k-slices,
// products -> bf16 A-fragments, MFMA vs LDS W^T, bias+LeakyReLU per valid
// edge-row, masked in-register segment sum. Epilogue: LN(node)+ReLU, store.
// Zero atomics; d_out written exactly once.
//
// launch_bounds(256,2): budget 256 unified regs/wave. Under (256,4) the
// unified file split left only 64 arch VGPRs (accum_offset=64) while the
// VALU working set needs ~80 -> per-chunk scratch spill = 2.86 GB HBM
// writes (R4/R5 counters). The 2nd arg only caps allocation; occupancy
// still follows actual usage.
__global__ __launch_bounds__(256, 2) void ngcf_seg(
    const float* __restrict__ xsrc, const float* __restrict__ xdst,
    const float* __restrict__ W, const float* __restrict__ bias,
    const int* __restrict__ offsets, const int* __restrict__ sorted,
    const float* __restrict__ lnw, const float* __restrict__ lnb,
    float* __restrict__ outp, int n_dst, int n_edges)
{
    __shared__ short Wt[128 * LDPAD];   // Wt[n][k] = W[k][n], bf16

    const int t = threadIdx.x;
    for (int i = t; i < 128 * 128; i += 256) {
        int k = i >> 7, n = i & 127;
        Wt[n * LDPAD + k] = f2bf(W[i]);
    }
    __syncthreads();   // only barrier; Wt read-only afterwards

    const int wv   = t >> 6;
    const int l    = t & 63;
    const int lo16 = l & 15;
    const int quad = l >> 4;

    float bn[8];
    #pragma unroll
    for (int n = 0; n < 8; n++) bn[n] = bias[n * 16 + lo16];

    for (int d = blockIdx.x * 4 + wv; d < n_dst; d += GRID_WAVES) {
        const int start = offsets[d];
        const int end   = (d + 1 < n_dst) ? offsets[d + 1] : n_edges;
        const int len   = end - start;

        // dst row k-slices for this lane (reused across chunks; fits now)
        const float4* pd = (const float4*)(xdst + ((size_t)d << 7));
        float4 dr[8];
        #pragma unroll
        for (int kt = 0; kt < 4; kt++) {
            dr[kt * 2 + 0] = pd[kt * 8 + quad * 2 + 0];
            dr[kt * 2 + 1] = pd[kt * 8 + quad * 2 + 1];
        }

        float nacc[8];
        #pragma unroll
        for (int n = 0; n < 8; n++) nacc[n] = 0.f;

        for (int c0 = 0; c0 < len; c0 += 16) {
            const int eidx = c0 + lo16;
            const int si = (eidx < len) ? sorted[start + eidx] : 0;
            const float4* ps = (const float4*)(xsrc + ((size_t)si << 7));

            f32x4 acc[8];
            #pragma unroll
            for (int n = 0; n < 8; n++) acc[n] = (f32x4){0.f, 0.f, 0.f, 0.f};

            #pragma unroll
            for (int kt = 0; kt < 4; kt++) {
                float4 a0 = ps[kt * 8 + quad * 2 + 0];
                float4 a1 = ps[kt * 8 + quad * 2 + 1];
                float4 c0v = dr[kt * 2 + 0];
                float4 c1v = dr[kt * 2 + 1];
                u32x4 up;
                up[0] = pack2f(a0.x * c0v.x, a0.y * c0v.y);
                up[1] = pack2f(a0.z * c0v.z, a0.w * c0v.w);
                up[2] = pack2f(a1.x * c1v.x, a1.y * c1v.y);
                up[3] = pack2f(a1.z * c1v.z, a1.w * c1v.w);
                bf16x8 afrag = __builtin_bit_cast(bf16x8, up);
                #pragma unroll
                for (int n = 0; n < 8; n++) {
                    bf16x8 bfrag = *(const bf16x8*)&Wt[(n * 16 + lo16) * LDPAD + kt * 32 + quad * 8];
                    acc[n] = __builtin_amdgcn_mfma_f32_16x16x32_bf16(afrag, bfrag, acc[n], 0, 0, 0);
                }
            }

            // bias + LeakyReLU per valid edge-row, masked segment sum.
            // C/D layout: col = n*16+lo16, row = quad*4+r (edge c0+row)
            const int rem = len - c0;
            #pragma unroll
            for (int r = 0; r < 4; r++) {
                const bool ok = (quad * 4 + r) < rem;
                #pragma unroll
                for (int n = 0; n < 8; n++) {
                    float v = acc[n][r] + bn[n];
                    v = v > 0.f ? v : NEG_SLOPE * v;
                    nacc[n] += ok ? v : 0.f;
                }
            }
        }

        // reduce partial sums across the 4 quads (rows live in different quads)
        #pragma unroll
        for (int n = 0; n < 8; n++) {
            nacc[n] += __shfl_xor(nacc[n], 16);
            nacc[n] += __shfl_xor(nacc[n], 32);
        }

        // fused LayerNorm(node) + ReLU. Lane (lo16,*) holds cols {n*16+lo16};
        // xor over bits 0..3 sums the 16 lo16 groups -> all 128 cols.
        float s1 = 0.f, s2 = 0.f;
        #pragma unroll
        for (int n = 0; n < 8; n++) { s1 += nacc[n]; s2 += nacc[n] * nacc[n]; }
        #pragma unroll
        for (int off = 1; off <= 8; off <<= 1) {
            s1 += __shfl_xor(s1, off);
            s2 += __shfl_xor(s2, off);
        }
        const float mu  = s1 * (1.0f / 128.0f);
        const float var = s2 * (1.0f / 128.0f) - mu * mu;
        const float rs  = rsqrtf(var + LN_EPS);

        // each lane stores 2 cols: n in {2*quad, 2*quad+1}
        const int n0 = 2 * quad, n1 = n0 + 1;
        const int col0 = n0 * 16 + lo16, col1 = n1 * 16 + lo16;
        float o0 = (nacc[n0] - mu) * rs * lnw[col0] + lnb[col0];
        float o1 = (nacc[n1] - mu) * rs * lnw[col1] + lnb[col1];
        float* rp = outp + ((size_t)d << 7);
        rp[col0] = fmaxf(o0, 0.f);
        rp[col1] = fmaxf(o1, 0.f);
    }
}

// ---------------- launch ----------------

static inline void run_relation(const float* xsrc, const float* xdst,
                                const float* W, const float* bias,
                                const int* src, const int* dst,
                                const float* lnw, const float* lnb,
                                float* outp, int n_dst,
                                int* counts, int* offsets, int* partial, int* sorted,
                                hipStream_t stream) {
    const int nb = (n_dst + 1023) / 1024;
    hipMemsetAsync(counts, 0, (size_t)n_dst * sizeof(int), stream);
    hist_k<<<dim3((E_EDGES + 255) / 256), dim3(256), 0, stream>>>(dst, counts, E_EDGES);
    scan_block_k<<<dim3(nb), dim3(1024), 0, stream>>>(counts, offsets, partial, n_dst);
    scan_part_k<<<dim3(1), dim3(128), 0, stream>>>(partial, nb);
    scan_add_k<<<dim3(nb), dim3(1024), 0, stream>>>(offsets, partial, counts, n_dst);
    scatter_k<<<dim3((E_EDGES + 255) / 256), dim3(256), 0, stream>>>(src, dst, offsets, counts, sorted, E_EDGES);
    ngcf_seg<<<dim3(GRID_BLOCKS), dim3(256), 0, stream>>>(
        xsrc, xdst, W, bias, offsets, sorted, lnw, lnb, outp, n_dst, E_EDGES);
}

extern "C" void kernel_launch(void* const* d_in, const int* in_sizes, int n_in,
                              void* d_out, int out_size, void* d_ws, size_t ws_size,
                              hipStream_t stream) {
    const float* x_user    = (const float*)d_in[0];
    const float* x_item    = (const float*)d_in[1];
    const float* W_ui      = (const float*)d_in[2];
    const float* b_ui      = (const float*)d_in[3];
    const float* W_iu      = (const float*)d_in[4];
    const float* b_iu      = (const float*)d_in[5];
    const float* ln_w_user = (const float*)d_in[6];
    const float* ln_b_user = (const float*)d_in[7];
    const float* ln_w_item = (const float*)d_in[8];
    const float* ln_b_item = (const float*)d_in[9];
    const int* esrc_ui = (const int*)d_in[10];
    const int* edst_ui = (const int*)d_in[11];
    const int* esrc_iu = (const int*)d_in[12];
    const int* edst_iu = (const int*)d_in[13];

    float* out = (float*)d_out;
    float* out_user = out;                          // N_USER x D
    float* out_item = out + (size_t)N_USER_C * D;   // N_ITEM x D

    // ws layout (ints): counts | offsets | partial | sorted  (~3.2 MB, reused)
    int* counts  = (int*)d_ws;
    int* offsets = counts + 100032;
    int* partial = offsets + 100032;
    int* sorted  = partial + 192;

    // relation user->item: aggregate at items, item LN params
    run_relation(x_user, x_item, W_ui, b_ui, esrc_ui, edst_ui,
                 ln_w_item, ln_b_item, out_item, N_ITEM_C,
                 counts, offsets, partial, sorted, stream);
    // relation item->user: aggregate at users, user LN params
    run_relation(x_item, x_user, W_iu, b_iu, esrc_iu, edst_iu,
                 ln_w_user, ln_b_user, out_user, N_USER_C,
                 counts, offsets, partial, sorted, stream);
}